// Round 13
// baseline (626.626 us; speedup 1.0000x reference)
//
#include <hip/hip_runtime.h>

#define NTOK 8192
#define DDIM 1024
#define HDIM 2048
#define NEXP 8

typedef unsigned short u16;
typedef short bf16x8 __attribute__((ext_vector_type(8)));
typedef float f32x4 __attribute__((ext_vector_type(4)));
typedef float float4_t __attribute__((ext_vector_type(4)));

__device__ __forceinline__ u16 f2bf(float f) {
  unsigned u = __float_as_uint(f);
  u += 0x7FFFu + ((u >> 16) & 1u);   // round-to-nearest-even
  return (u16)(u >> 16);
}

#define GLOAD_LDS16(gp, lp)                                                     \
  __builtin_amdgcn_global_load_lds(                                             \
      (const __attribute__((address_space(1))) unsigned int*)(gp),              \
      (__attribute__((address_space(3))) unsigned int*)(lp), 16, 0, 0)

#define VMW(n) asm volatile("s_waitcnt vmcnt(" #n ")" ::: "memory")
#define ENTRYB()                                                                \
  { __builtin_amdgcn_s_barrier(); __builtin_amdgcn_sched_barrier(0); }

// ------------------------------------------------ fused x->bf16 convert + gate
__global__ void k_prep(const float* __restrict__ x, const float* __restrict__ Wg,
                       const float* __restrict__ bg,
                       u16* __restrict__ xb, float* __restrict__ gate) {
  const int tok = (blockIdx.x * 256 + threadIdx.x) >> 6;
  const int lane = threadIdx.x & 63;
  const float* xr = x + (size_t)tok * DDIM;
  u16* xo = xb + (size_t)tok * DDIM;
  float s[NEXP];
#pragma unroll
  for (int e = 0; e < NEXP; ++e) s[e] = 0.f;
#pragma unroll
  for (int it = 0; it < 2; ++it) {
    const int d0 = lane * 8 + it * 512;
    float4_t v0 = *(const float4_t*)(xr + d0);
    float4_t v1 = *(const float4_t*)(xr + d0 + 4);
    union { bf16x8 v; u16 h[8]; } u;
    u.h[0] = f2bf(v0.x); u.h[1] = f2bf(v0.y); u.h[2] = f2bf(v0.z); u.h[3] = f2bf(v0.w);
    u.h[4] = f2bf(v1.x); u.h[5] = f2bf(v1.y); u.h[6] = f2bf(v1.z); u.h[7] = f2bf(v1.w);
    *(bf16x8*)(xo + d0) = u.v;
    float xv[8] = {v0.x, v0.y, v0.z, v0.w, v1.x, v1.y, v1.z, v1.w};
#pragma unroll
    for (int j = 0; j < 8; ++j) {
      const float4_t w0 = *(const float4_t*)(Wg + (size_t)(d0 + j) * NEXP);
      const float4_t w1 = *(const float4_t*)(Wg + (size_t)(d0 + j) * NEXP + 4);
      s[0] += xv[j] * w0.x; s[1] += xv[j] * w0.y;
      s[2] += xv[j] * w0.z; s[3] += xv[j] * w0.w;
      s[4] += xv[j] * w1.x; s[5] += xv[j] * w1.y;
      s[6] += xv[j] * w1.z; s[7] += xv[j] * w1.w;
    }
  }
#pragma unroll
  for (int off = 32; off; off >>= 1)
#pragma unroll
    for (int e = 0; e < NEXP; ++e) s[e] += __shfl_down(s[e], off);
  if (lane == 0) {
#pragma unroll
    for (int e = 0; e < NEXP; ++e) gate[(size_t)tok * NEXP + e] = s[e] + bg[e];
  }
}

// ------------- vectorized transpose+convert: out[z*oexp + c*orstride + r] = in[z][r][c]
__global__ void k_transpose(const float* __restrict__ in, u16* __restrict__ out,
                            int R, int C, size_t oexp, int orstride) {
  __shared__ float t[64][65];
  const int rb = blockIdx.x * 64, cb = blockIdx.y * 64;
  const float* pin = in + (size_t)blockIdx.z * R * C;
  u16* pout = out + (size_t)blockIdx.z * oexp;
  const int tid = threadIdx.x;
  {
    const int r = tid >> 4;
    const int c4 = (tid & 15) * 4;
#pragma unroll
    for (int i = 0; i < 4; ++i) {
      float4_t v = *(const float4_t*)(pin + (size_t)(rb + r + 16 * i) * C + cb + c4);
      t[r + 16 * i][c4 + 0] = v.x;
      t[r + 16 * i][c4 + 1] = v.y;
      t[r + 16 * i][c4 + 2] = v.z;
      t[r + 16 * i][c4 + 3] = v.w;
    }
  }
  __syncthreads();
  {
    const int oc = tid >> 3;
    const int r8 = (tid & 7) * 8;
#pragma unroll
    for (int jp = 0; jp < 2; ++jp) {
      const int ocol = oc + 32 * jp;
      union { bf16x8 v; u16 h[8]; } u;
#pragma unroll
      for (int k = 0; k < 8; ++k) u.h[k] = f2bf(t[r8 + k][ocol]);
      *(bf16x8*)(pout + (size_t)(cb + ocol) * orstride + rb + r8) = u.v;
    }
  }
}

// ============ unified lag-one GEMM: 128x256 tile, 2 fat phases; each phase's
// MFMA consumes operands read the PREVIOUS phase (A reg-double-buffered), so
// ds_reads issue dependency-free and overlap the MFMA cluster.
// MODE 1: h'[m][ldc] = bf16(gate*relu(acc+bias)) ; MODE 2: out f32 (+)= acc (+gate.b2)
// BCH: B K-dim spans per-expert [e][*][HDIM] blocks (else flat, ldb row stride)
template <int MODE, int BCH>
__global__ __launch_bounds__(512, 2) void k_lag(
    const u16* __restrict__ A, int lda,
    const u16* __restrict__ Bt, int ldb,
    const float* __restrict__ bias,
    const float* __restrict__ gate, int ebase,
    void* __restrict__ Cout, int ldc,
    int accum, int nk, int ca, int cb, int cgcols) {
  __shared__ __align__(16) u16 lds[49152];   // 96 KiB: 2 buf x (A 128 | B 256) x 64
  const int tid = threadIdx.x, lane = tid & 63, wid = tid >> 6;
  const int wm = wid >> 2, wn = wid & 3;
  // XCD supertile: chunk = ca x cb tiles, tn-inner
  const int wg = blockIdx.x;
  const int xcd = wg & 7, lo = wg >> 3;
  const int cr = xcd / cgcols, cc = xcd % cgcols;
  const int tm = cr * ca + lo / cb;
  const int tn = cc * cb + lo % cb;
  const int bm = tm * 128, bn = tn * 256;

  const int srow = tid >> 3;
  const int scol = ((tid & 7) ^ (srow & 7)) << 3;
  const u16* gA = A + (size_t)(bm + srow) * lda + scol;
  const u16* gB = Bt + (size_t)(bn + srow) * ldb + scol;
  const int dofs = wid * 512;

  u16* aB0 = lds;          u16* bB0 = lds + 8192;
  u16* aB1 = lds + 24576;  u16* bB1 = lds + 32768;

  const int fr = lane & 15, fq = lane >> 4, xr = fr & 7;
  const int so0 = ((0 + fq) ^ xr) << 3;
  const int so1 = ((4 + fq) ^ xr) << 3;

  f32x4 acc[2][4][2] = {};
  bf16x8 avA[8], avB[8], bv0[2][2], bv1[2][2];

#define BOFF(ts) (BCH ? ((size_t)((ts) >> 5) * ((size_t)DDIM * HDIM) +          \
                         (size_t)((ts) & 31) * 64)                              \
                      : (size_t)(ts) * 64)
#define L_SA(dst, ts)                                                           \
  { GLOAD_LDS16(gA + (size_t)(ts) * 64, (dst) + dofs);                          \
    GLOAD_LDS16(gA + (size_t)64 * lda + (size_t)(ts) * 64,                      \
                (dst) + 4096 + dofs); }
#define L_SB(dst, hh, ts)                                                       \
  { GLOAD_LDS16(gB + (size_t)((hh)*128     ) * ldb + BOFF(ts),                  \
                (dst) + ((hh)*128     ) * 64 + dofs);                           \
    GLOAD_LDS16(gB + (size_t)((hh)*128 + 64) * ldb + BOFF(ts),                  \
                (dst) + ((hh)*128 + 64) * 64 + dofs); }
#define L_RDA(DST, src)                                                         \
  { _Pragma("unroll") for (int i_ = 0; i_ < 4; ++i_) {                          \
      const int rb_ = (wm * 64 + i_ * 16 + fr) << 6;                            \
      (DST)[i_ * 2 + 0] = *(const bf16x8*)((src) + rb_ + so0);                  \
      (DST)[i_ * 2 + 1] = *(const bf16x8*)((src) + rb_ + so1); } }
#define L_RDB(DST, src, NH)                                                     \
  { _Pragma("unroll") for (int n_ = 0; n_ < 2; ++n_) {                          \
      const int rb_ = ((NH)*128 + wn * 32 + n_ * 16 + fr) << 6;                 \
      (DST)[n_][0] = *(const bf16x8*)((src) + rb_ + so0);                       \
      (DST)[n_][1] = *(const bf16x8*)((src) + rb_ + so1); } }
#define L_MMA(Q, AV, BV)                                                        \
  { __builtin_amdgcn_s_setprio(1);                                              \
    _Pragma("unroll") for (int k_ = 0; k_ < 2; ++k_)                            \
    _Pragma("unroll") for (int i_ = 0; i_ < 4; ++i_)                            \
    _Pragma("unroll") for (int n_ = 0; n_ < 2; ++n_)                            \
      acc[Q][i_][n_] = __builtin_amdgcn_mfma_f32_16x16x32_bf16(                 \
          (AV)[i_ * 2 + k_], (BV)[n_][k_], acc[Q][i_][n_], 0, 0, 0);            \
    __builtin_amdgcn_s_setprio(0); }

// lag-one iteration: p0 reads A(t),B0(t) & computes N1(t-1); p1 reads B1(t)
// & computes N0(t). Stages target the opposite buffer only (race-safe: the
// B1(t-1) LDS region is overwritten at p1(t), after the p1 barrier which
// implies all waves issued MFMA N1(t-1), hence their B1(t-1) reads completed).
#define L_ITER(T, AV, AVP, aCur, bCur, aNx, bNx)                                \
  {                                                                             \
    VMW(2); ENTRYB();                                                           \
    L_RDA(AV, aCur);                                                            \
    L_RDB(bv0, bCur, 0);                                                        \
    if ((T) + 1 < nk) { L_SA(aNx, (T) + 1); L_SB(bNx, 0, (T) + 1); }            \
    if ((T) > 0) L_MMA(1, AVP, bv1);                                            \
    if ((T) + 1 < nk) { VMW(4); } else { VMW(0); }                              \
    ENTRYB();                                                                   \
    L_RDB(bv1, bCur, 1);                                                        \
    if ((T) + 1 < nk) L_SB(bNx, 1, (T) + 1);                                    \
    L_MMA(0, AV, bv0);                                                          \
  }

  // prologue: stage tile 0 only (A, B0, B1) -> 6 loads in flight
  L_SA(aB0, 0); L_SB(bB0, 0, 0); L_SB(bB0, 1, 0);

#pragma unroll 1
  for (int tt = 0; tt < nk; tt += 2) {
    L_ITER(tt,     avA, avB, aB0, bB0, aB1, bB1);
    L_ITER(tt + 1, avB, avA, aB1, bB1, aB0, bB0);
  }
  // tail: N1 of the last tile (nk even -> last AV was avB, bv1 holds B1(nk-1))
  L_MMA(1, avB, bv1);

  // ---------------- epilogue; C/D layout: col=lane&15, row=(lane>>4)*4+j
  if (MODE == 1) {
    u16* O = (u16*)Cout;
#pragma unroll
    for (int NH = 0; NH < 2; ++NH) {
      const int cb0 = bn + NH * 128 + wn * 32;
      const int e = ebase + (cb0 >> 11);   // 32-col wave slice within one expert
      float bcol[2];
#pragma unroll
      for (int n = 0; n < 2; ++n) bcol[n] = bias[cb0 + n * 16 + fr];
#pragma unroll
      for (int i = 0; i < 4; ++i) {
#pragma unroll
        for (int j = 0; j < 4; ++j) {
          const int r = bm + wm * 64 + i * 16 + fq * 4 + j;
          const float g = gate[(size_t)r * NEXP + e];
#pragma unroll
          for (int n = 0; n < 2; ++n) {
            float v = fmaxf(acc[NH][i][n][j] + bcol[n], 0.f) * g;
            O[(size_t)r * ldc + cb0 + n * 16 + fr] = f2bf(v);
          }
        }
      }
    }
  } else {
    float* O = (float*)Cout;
    float b2c[2][2][NEXP];
    if (!accum) {
#pragma unroll
      for (int nh = 0; nh < 2; ++nh)
#pragma unroll
        for (int n = 0; n < 2; ++n)
#pragma unroll
          for (int e = 0; e < NEXP; ++e)
            b2c[nh][n][e] = bias[(size_t)e * DDIM + bn + nh * 128 + wn * 32 + n * 16 + fr];
    }
#pragma unroll
    for (int NH = 0; NH < 2; ++NH) {
      const int cb0 = bn + NH * 128 + wn * 32;
#pragma unroll
      for (int i = 0; i < 4; ++i) {
#pragma unroll
        for (int j = 0; j < 4; ++j) {
          const int r = bm + wm * 64 + i * 16 + fq * 4 + j;
          if (!accum) {
            float g8[NEXP];
#pragma unroll
            for (int e = 0; e < NEXP; ++e) g8[e] = gate[(size_t)r * NEXP + e];
#pragma unroll
            for (int n = 0; n < 2; ++n) {
              float v = acc[NH][i][n][j];
#pragma unroll
              for (int e = 0; e < NEXP; ++e) v += g8[e] * b2c[NH][n][e];
              O[(size_t)r * DDIM + cb0 + n * 16 + fr] = v;
            }
          } else {
#pragma unroll
            for (int n = 0; n < 2; ++n) {
              const size_t idx = (size_t)r * DDIM + cb0 + n * 16 + fr;
              O[idx] += acc[NH][i][n][j];
            }
          }
        }
      }
    }
  }
#undef BOFF
#undef L_SA
#undef L_SB
#undef L_RDA
#undef L_RDB
#undef L_MMA
#undef L_ITER
}

extern "C" void kernel_launch(void* const* d_in, const int* in_sizes, int n_in,
                              void* d_out, int out_size, void* d_ws, size_t ws_size,
                              hipStream_t stream) {
  (void)in_sizes; (void)n_in; (void)out_size;
  const float* x  = (const float*)d_in[0];   // [N, D]
  const float* W1 = (const float*)d_in[1];   // [E, D, H]
  const float* b1 = (const float*)d_in[2];   // [E, H]
  const float* W2 = (const float*)d_in[3];   // [E, H, D]
  const float* b2 = (const float*)d_in[4];   // [E, D]
  const float* Wg = (const float*)d_in[5];   // [D, E]
  const float* bg = (const float*)d_in[6];   // [E]
  float* out = (float*)d_out;                // [N, D]

  size_t o_xb   = 0;
  size_t o_w1t  = o_xb  + (size_t)NTOK * DDIM * 2;          // xb   bf16 [N,D]
  size_t o_w2t  = o_w1t + (size_t)NEXP * HDIM * DDIM * 2;   // W1t  bf16 [E*H, D]
  size_t o_gate = o_w2t + (size_t)NEXP * DDIM * HDIM * 2;   // W2t  bf16 [E][D][H]
  size_t o_h    = o_gate + (size_t)NTOK * NEXP * 4;         // gate f32  [N, E]

  int G = 4;                                                 // experts per group
  if (o_h + (size_t)NTOK * G * HDIM * 2 > ws_size) G = 2;
  if (o_h + (size_t)NTOK * G * HDIM * 2 > ws_size) return;

  u16*   xb   = (u16*)((char*)d_ws + o_xb);
  u16*   W1t  = (u16*)((char*)d_ws + o_w1t);
  u16*   W2t  = (u16*)((char*)d_ws + o_w2t);
  float* gate = (float*)((char*)d_ws + o_gate);
  u16*   hbuf = (u16*)((char*)d_ws + o_h);

  k_prep<<<NTOK / 4, 256, 0, stream>>>(x, Wg, bg, xb, gate);
  dim3 g1(DDIM / 64, HDIM / 64, NEXP);
  k_transpose<<<g1, 256, 0, stream>>>(W1, W1t, DDIM, HDIM, (size_t)HDIM * DDIM, DDIM);
  dim3 g2(HDIM / 64, DDIM / 64, NEXP);
  k_transpose<<<g2, 256, 0, stream>>>(W2, W2t, HDIM, DDIM, (size_t)DDIM * HDIM, HDIM);

  const int KW = G * HDIM;                     // 8192 or 4096
  // GEMM1 supertile: per-XCD B-band = 8 tn x 256 cols x 2KB = 4 MB (L2-fit)
  const int ca1 = (G == 4) ? 32 : 16;          // chunk tm rows
  const int cg1 = (G == 4) ? 4 : 2;            // chunk-grid cols
  for (int g = 0; g < NEXP / G; ++g) {
    // GEMM1: M=8192, N=KW, K=1024; grid 64tm x (KW/256)tn
    k_lag<1, 0><<<(NTOK / 128) * (KW / 256), 512, 0, stream>>>(
        xb, DDIM, W1t + (size_t)g * KW * DDIM, DDIM,
        b1 + (size_t)g * KW, gate, g * G,
        hbuf, KW, 0, DDIM / 64, ca1, 8, cg1);
    // GEMM2: M=8192, N=1024, K=KW; grid 64tm x 4tn = 256
    k_lag<2, 1><<<256, 512, 0, stream>>>(
        hbuf, KW, W2t + (size_t)g * G * DDIM * HDIM, HDIM,
        b2, gate, 0,
        out, DDIM, g > 0, KW / 64, 8, 4, 1);
  }
}

// Round 14
// 572.755 us; speedup vs baseline: 1.0941x; 1.0941x over previous
//
#include <hip/hip_runtime.h>

#define NTOK 8192
#define DDIM 1024
#define HDIM 2048
#define NEXP 8
#define G1_NKT 16               // GEMM1 K=1024 / 64

typedef unsigned short u16;
typedef short bf16x8 __attribute__((ext_vector_type(8)));
typedef float f32x4 __attribute__((ext_vector_type(4)));
typedef float float4_t __attribute__((ext_vector_type(4)));

__device__ __forceinline__ u16 f2bf(float f) {
  unsigned u = __float_as_uint(f);
  u += 0x7FFFu + ((u >> 16) & 1u);   // round-to-nearest-even
  return (u16)(u >> 16);
}

#define GLOAD_LDS16(gp, lp)                                                     \
  __builtin_amdgcn_global_load_lds(                                             \
      (const __attribute__((address_space(1))) unsigned int*)(gp),              \
      (__attribute__((address_space(3))) unsigned int*)(lp), 16, 0, 0)

#define VMW(n) asm volatile("s_waitcnt vmcnt(" #n ")" ::: "memory")
#define ENTRYB()                                                                \
  { __builtin_amdgcn_s_barrier(); __builtin_amdgcn_sched_barrier(0); }

// ------------------------------------------------ fused x->bf16 convert + gate
__global__ void k_prep(const float* __restrict__ x, const float* __restrict__ Wg,
                       const float* __restrict__ bg,
                       u16* __restrict__ xb, float* __restrict__ gate) {
  const int tok = (blockIdx.x * 256 + threadIdx.x) >> 6;
  const int lane = threadIdx.x & 63;
  const float* xr = x + (size_t)tok * DDIM;
  u16* xo = xb + (size_t)tok * DDIM;
  float s[NEXP];
#pragma unroll
  for (int e = 0; e < NEXP; ++e) s[e] = 0.f;
#pragma unroll
  for (int it = 0; it < 2; ++it) {
    const int d0 = lane * 8 + it * 512;
    float4_t v0 = *(const float4_t*)(xr + d0);
    float4_t v1 = *(const float4_t*)(xr + d0 + 4);
    union { bf16x8 v; u16 h[8]; } u;
    u.h[0] = f2bf(v0.x); u.h[1] = f2bf(v0.y); u.h[2] = f2bf(v0.z); u.h[3] = f2bf(v0.w);
    u.h[4] = f2bf(v1.x); u.h[5] = f2bf(v1.y); u.h[6] = f2bf(v1.z); u.h[7] = f2bf(v1.w);
    *(bf16x8*)(xo + d0) = u.v;
    float xv[8] = {v0.x, v0.y, v0.z, v0.w, v1.x, v1.y, v1.z, v1.w};
#pragma unroll
    for (int j = 0; j < 8; ++j) {
      const float4_t w0 = *(const float4_t*)(Wg + (size_t)(d0 + j) * NEXP);
      const float4_t w1 = *(const float4_t*)(Wg + (size_t)(d0 + j) * NEXP + 4);
      s[0] += xv[j] * w0.x; s[1] += xv[j] * w0.y;
      s[2] += xv[j] * w0.z; s[3] += xv[j] * w0.w;
      s[4] += xv[j] * w1.x; s[5] += xv[j] * w1.y;
      s[6] += xv[j] * w1.z; s[7] += xv[j] * w1.w;
    }
  }
#pragma unroll
  for (int off = 32; off; off >>= 1)
#pragma unroll
    for (int e = 0; e < NEXP; ++e) s[e] += __shfl_down(s[e], off);
  if (lane == 0) {
#pragma unroll
    for (int e = 0; e < NEXP; ++e) gate[(size_t)tok * NEXP + e] = s[e] + bg[e];
  }
}

// ------------- vectorized transpose+convert: out[z*oexp + c*orstride + r] = in[z][r][c]
__global__ void k_transpose(const float* __restrict__ in, u16* __restrict__ out,
                            int R, int C, size_t oexp, int orstride) {
  __shared__ float t[64][65];
  const int rb = blockIdx.x * 64, cb = blockIdx.y * 64;
  const float* pin = in + (size_t)blockIdx.z * R * C;
  u16* pout = out + (size_t)blockIdx.z * oexp;
  const int tid = threadIdx.x;
  {
    const int r = tid >> 4;
    const int c4 = (tid & 15) * 4;
#pragma unroll
    for (int i = 0; i < 4; ++i) {
      float4_t v = *(const float4_t*)(pin + (size_t)(rb + r + 16 * i) * C + cb + c4);
      t[r + 16 * i][c4 + 0] = v.x;
      t[r + 16 * i][c4 + 1] = v.y;
      t[r + 16 * i][c4 + 2] = v.z;
      t[r + 16 * i][c4 + 3] = v.w;
    }
  }
  __syncthreads();
  {
    const int oc = tid >> 3;
    const int r8 = (tid & 7) * 8;
#pragma unroll
    for (int jp = 0; jp < 2; ++jp) {
      const int ocol = oc + 32 * jp;
      union { bf16x8 v; u16 h[8]; } u;
#pragma unroll
      for (int k = 0; k < 8; ++k) u.h[k] = f2bf(t[r8 + k][ocol]);
      *(bf16x8*)(pout + (size_t)(cb + ocol) * orstride + rb + r8) = u.v;
    }
  }
}

// ============ GEMM1: 256x256 tile, 4-phase snake + LAG-ONE: each phase's MFMA
// consumes operands read in the PREVIOUS phase (A/B reg-alternating buffers),
// so ds_reads issue dependency-free and overlap the MFMA clusters.
// h'[m][KW] = bf16(gate * relu(x . W1t^T + b1))
__global__ __launch_bounds__(512, 2) void k_g1(
    const u16* __restrict__ A, const u16* __restrict__ Bt,
    const float* __restrict__ bias, const float* __restrict__ gate,
    int ebase, u16* __restrict__ Cout, int KW, int ca, int cgcols) {
  __shared__ __align__(16) u16 lds[65536];   // 128 KiB: 2 buf x (A 256 | B 256) x 64
  const int tid = threadIdx.x, lane = tid & 63, wid = tid >> 6;
  const int wm = wid >> 2, wn = wid & 3;
  // XCD supertile: chunks of ca x 8, tn-inner
  const int wg = blockIdx.x;
  const int xcd = wg & 7, lo = wg >> 3;
  const int cr = xcd / cgcols, cc = xcd % cgcols;
  const int tm = cr * ca + (lo >> 3);
  const int tn = cc * 8 + (lo & 7);
  const int bm = tm * 256, bn = tn * 256;

  const int srow = tid >> 3;
  const int scol = ((tid & 7) ^ (srow & 7)) << 3;
  const u16* gA = A + (size_t)(bm + srow) * 1024 + scol;
  const u16* gB = Bt + (size_t)(bn + srow) * 1024 + scol;
  const int dofs = wid * 512;

  u16* aB0 = lds;          u16* bB0 = lds + 16384;
  u16* aB1 = lds + 32768;  u16* bB1 = lds + 49152;

  const int fr = lane & 15, fq = lane >> 4, xr = fr & 7;
  const int so0 = ((0 + fq) ^ xr) << 3;
  const int so1 = ((4 + fq) ^ xr) << 3;

  f32x4 acc[4][4][2] = {};
  bf16x8 avX[8], avY[8], bvU[4], bvV[4];   // operand double-buffers (lag-one)

#define G1_SA(dst, hh, ts)                                                      \
  { GLOAD_LDS16(gA + (size_t)((hh)*128     ) * 1024 + (size_t)(ts) * 64,        \
                (dst) + ((hh)*128     ) * 64 + dofs);                           \
    GLOAD_LDS16(gA + (size_t)((hh)*128 + 64) * 1024 + (size_t)(ts) * 64,        \
                (dst) + ((hh)*128 + 64) * 64 + dofs); }
#define G1_SB(dst, hh, ts)                                                      \
  { GLOAD_LDS16(gB + (size_t)((hh)*128     ) * 1024 + (size_t)(ts) * 64,        \
                (dst) + ((hh)*128     ) * 64 + dofs);                           \
    GLOAD_LDS16(gB + (size_t)((hh)*128 + 64) * 1024 + (size_t)(ts) * 64,        \
                (dst) + ((hh)*128 + 64) * 64 + dofs); }
// reads into explicit buffers (kk-ordered: so0 pair then so1 pair)
#define RD_A(DST, src, MH)                                                      \
  { _Pragma("unroll") for (int i_ = 0; i_ < 4; ++i_) {                          \
      const int rb_ = ((MH)*128 + wm * 64 + i_ * 16 + fr) << 6;                 \
      (DST)[i_ * 2 + 0] = *(const bf16x8*)((src) + rb_ + so0);                  \
      (DST)[i_ * 2 + 1] = *(const bf16x8*)((src) + rb_ + so1); } }
#define RD_B(DST, src, NH)                                                      \
  { _Pragma("unroll") for (int n_ = 0; n_ < 2; ++n_) {                          \
      const int rb_ = ((NH)*128 + wn * 32 + n_ * 16 + fr) << 6;                 \
      (DST)[n_ * 2 + 0] = *(const bf16x8*)((src) + rb_ + so0);                  \
      (DST)[n_ * 2 + 1] = *(const bf16x8*)((src) + rb_ + so1); } }
#define MMA16(Q, AV, BV)                                                        \
  { __builtin_amdgcn_s_setprio(1);                                              \
    _Pragma("unroll") for (int k_ = 0; k_ < 2; ++k_)                            \
    _Pragma("unroll") for (int i_ = 0; i_ < 4; ++i_)                            \
    _Pragma("unroll") for (int n_ = 0; n_ < 2; ++n_)                            \
      acc[Q][i_][n_] = __builtin_amdgcn_mfma_f32_16x16x32_bf16(                 \
          (AV)[i_ * 2 + k_], (BV)[n_ * 2 + k_], acc[Q][i_][n_], 0, 0, 0);       \
    __builtin_amdgcn_s_setprio(0); }

// Lag-one snake tile. Reads: p0 A0->Aa,B0->bvU; p1 A1->Ab; p2 B1->bvV;
// p3 A0re->Aa. MMA: p0 issues M0N1(t-1) [prev r3 = current Ab, bvV];
// p1 M0N0(t) [Aa,bvU]; p2 M1N0(t) [Ab,bvU]; p3 M1N1(t) [Ab,bvV].
// vmcnt/barrier/stage schedule identical to the round-12 proven snake.
#define G1_TILE(T, Aa, Ab)                                                      \
  {                                                                             \
    const bool s1_ = ((T) + 1 < G1_NKT);                                        \
    VMW(4); ENTRYB();                                                           \
    RD_A(Aa, aC_, 0); RD_B(bvU, bC_, 0);                                        \
    if (s1_) G1_SA(aN_, 0, (T) + 1);                                            \
    if ((T) > 0) MMA16(1, Ab, bvV);                                             \
    if (s1_) { VMW(4); } else { VMW(2); }                                       \
    ENTRYB();                                                                   \
    RD_A(Ab, aC_, 1);                                                           \
    if (s1_) G1_SB(bN_, 0, (T) + 1);                                            \
    MMA16(0, Aa, bvU);                                                          \
    if (s1_) { VMW(4); } else { VMW(0); }                                       \
    ENTRYB();                                                                   \
    RD_B(bvV, bC_, 1);                                                          \
    if (s1_) G1_SA(aN_, 1, (T) + 1);                                            \
    MMA16(2, Ab, bvU);                                                          \
    RD_A(Aa, aC_, 0);                                                           \
    if (s1_) G1_SB(bN_, 1, (T) + 1);                                            \
    MMA16(3, Ab, bvV);                                                          \
    u16* tp_;                                                                   \
    tp_ = aC_; aC_ = aN_; aN_ = tp_;                                            \
    tp_ = bC_; bC_ = bN_; bN_ = tp_;                                            \
  }

  // prologue: tile0, issue order A0,B0,A1,B1 (matches steady-state order)
  G1_SA(aB0, 0, 0); G1_SB(bB0, 0, 0); G1_SA(aB0, 1, 0); G1_SB(bB0, 1, 0);

  u16 *aC_ = aB0, *bC_ = bB0, *aN_ = aB1, *bN_ = bB1;

#pragma unroll 1
  for (int tt = 0; tt < G1_NKT; tt += 2) {
    G1_TILE(tt,     avX, avY);
    G1_TILE(tt + 1, avY, avX);
  }
  // tail: M0N1 of the last tile (last tile had Aa=avY holding its p3 A0 re-read)
  MMA16(1, avY, bvV);

  // epilogue; C/D layout: col=lane&15, row=(lane>>4)*4+j
#pragma unroll
  for (int q = 0; q < 4; ++q) {
    const int MH = q >> 1, NH = q & 1;
    const int cb0 = bn + NH * 128 + wn * 32;
    const int e = ebase + (cb0 >> 11);
    float bcol[2];
#pragma unroll
    for (int n = 0; n < 2; ++n) bcol[n] = bias[cb0 + n * 16 + fr];
#pragma unroll
    for (int i = 0; i < 4; ++i) {
#pragma unroll
      for (int j = 0; j < 4; ++j) {
        const int r = bm + MH * 128 + wm * 64 + i * 16 + fq * 4 + j;
        const float g = gate[(size_t)r * NEXP + e];
#pragma unroll
        for (int n = 0; n < 2; ++n) {
          float v = fmaxf(acc[q][i][n][j] + bcol[n], 0.f) * g;
          Cout[(size_t)r * KW + cb0 + n * 16 + fr] = f2bf(v);
        }
      }
    }
  }
#undef G1_SA
#undef G1_SB
#undef RD_A
#undef RD_B
#undef MMA16
#undef G1_TILE
}

// ============ GEMM2: 128x256 tile, lag-one pipeline (round-12 proven version)
// out[m][1024] (+)= h'[m][KW] . W2t^T  (+ sum_e gate*b2 when !accum)
__global__ __launch_bounds__(512, 2) void k_g2(
    const u16* __restrict__ A, const u16* __restrict__ Bt,
    const float* __restrict__ bias, const float* __restrict__ gate,
    float* __restrict__ Cout, int accum, int KW, int nk) {
  __shared__ __align__(16) u16 lds[49152];   // 96 KiB: 2 buf x (A 128 | B 256) x 64
  const int tid = threadIdx.x, lane = tid & 63, wid = tid >> 6;
  const int wm = wid >> 2, wn = wid & 3;
  // XCD supertile: 64tm x 4tn grid; 8 chunks of 8x4, tn-inner
  const int wg = blockIdx.x;
  const int xcd = wg & 7, lo = wg >> 3;
  const int tm = xcd * 8 + (lo >> 2);
  const int tn = lo & 3;
  const int bm = tm * 128, bn = tn * 256;

  const int srow = tid >> 3;
  const int scol = ((tid & 7) ^ (srow & 7)) << 3;
  const u16* gA = A + (size_t)(bm + srow) * KW + scol;
  const u16* gB = Bt + (size_t)(bn + srow) * HDIM + scol;
  const int dofs = wid * 512;

  u16* aB0 = lds;          u16* bB0 = lds + 8192;
  u16* aB1 = lds + 24576;  u16* bB1 = lds + 32768;

  const int fr = lane & 15, fq = lane >> 4, xr = fr & 7;
  const int so0 = ((0 + fq) ^ xr) << 3;
  const int so1 = ((4 + fq) ^ xr) << 3;

  f32x4 acc[2][4][2] = {};
  bf16x8 avA[8], avB[8], bv0[2][2], bv1[2][2];

#define G2_BOFF(ts) ((size_t)((ts) >> 5) * ((size_t)DDIM * HDIM) +              \
                     (size_t)((ts) & 31) * 64)
#define G2_SA(dst, ts)                                                          \
  { GLOAD_LDS16(gA + (size_t)(ts) * 64, (dst) + dofs);                          \
    GLOAD_LDS16(gA + (size_t)64 * KW + (size_t)(ts) * 64,                       \
                (dst) + 4096 + dofs); }
#define G2_SB(dst, hh, ts)                                                      \
  { GLOAD_LDS16(gB + (size_t)((hh)*128     ) * HDIM + G2_BOFF(ts),              \
                (dst) + ((hh)*128     ) * 64 + dofs);                           \
    GLOAD_LDS16(gB + (size_t)((hh)*128 + 64) * HDIM + G2_BOFF(ts),              \
                (dst) + ((hh)*128 + 64) * 64 + dofs); }
#define G2_RDA_TO(DST, src)                                                     \
  { _Pragma("unroll") for (int i_ = 0; i_ < 4; ++i_) {                          \
      const int rb_ = (wm * 64 + i_ * 16 + fr) << 6;                            \
      (DST)[i_ * 2 + 0] = *(const bf16x8*)((src) + rb_ + so0);                  \
      (DST)[i_ * 2 + 1] = *(const bf16x8*)((src) + rb_ + so1); } }
#define G2_RDB_TO(DST, src, NH)                                                 \
  { _Pragma("unroll") for (int n_ = 0; n_ < 2; ++n_) {                          \
      const int rb_ = ((NH)*128 + wn * 32 + n_ * 16 + fr) << 6;                 \
      (DST)[n_][0] = *(const bf16x8*)((src) + rb_ + so0);                       \
      (DST)[n_][1] = *(const bf16x8*)((src) + rb_ + so1); } }
#define G2_MMA(Q, AV, BV)                                                       \
  { __builtin_amdgcn_s_setprio(1);                                              \
    _Pragma("unroll") for (int k_ = 0; k_ < 2; ++k_)                            \
    _Pragma("unroll") for (int i_ = 0; i_ < 4; ++i_)                            \
    _Pragma("unroll") for (int n_ = 0; n_ < 2; ++n_)                            \
      acc[Q][i_][n_] = __builtin_amdgcn_mfma_f32_16x16x32_bf16(                 \
          (AV)[i_ * 2 + k_], (BV)[n_][k_], acc[Q][i_][n_], 0, 0, 0);            \
    __builtin_amdgcn_s_setprio(0); }

#define G2_ITER(T, AV, AVP, aCur, bCur, aNx, bNx)                               \
  {                                                                             \
    VMW(2); ENTRYB();                                                           \
    G2_RDA_TO(AV, aCur);                                                        \
    G2_RDB_TO(bv0, bCur, 0);                                                    \
    if ((T) + 1 < nk) { G2_SA(aNx, (T) + 1); G2_SB(bNx, 0, (T) + 1); }          \
    if ((T) > 0) G2_MMA(1, AVP, bv1);                                           \
    if ((T) + 1 < nk) { VMW(4); } else { VMW(0); }                              \
    ENTRYB();                                                                   \
    G2_RDB_TO(bv1, bCur, 1);                                                    \
    if ((T) + 1 < nk) G2_SB(bNx, 1, (T) + 1);                                   \
    G2_MMA(0, AV, bv0);                                                         \
  }

  // prologue: stage tile 0 only (A, B0, B1) -> 6 loads in flight
  G2_SA(aB0, 0); G2_SB(bB0, 0, 0); G2_SB(bB0, 1, 0);

#pragma unroll 1
  for (int tt = 0; tt < nk; tt += 2) {
    G2_ITER(tt,     avA, avB, aB0, bB0, aB1, bB1);
    G2_ITER(tt + 1, avB, avA, aB1, bB1, aB0, bB0);
  }
  // tail: N1 of the last tile
  G2_MMA(1, avB, bv1);

  // epilogue
  float b2c[2][2][NEXP];
  if (!accum) {
#pragma unroll
    for (int nh = 0; nh < 2; ++nh)
#pragma unroll
      for (int n = 0; n < 2; ++n)
#pragma unroll
        for (int e = 0; e < NEXP; ++e)
          b2c[nh][n][e] = bias[(size_t)e * DDIM + bn + nh * 128 + wn * 32 + n * 16 + fr];
  }
#pragma unroll
  for (int NH = 0; NH < 2; ++NH) {
    const int cb0 = bn + NH * 128 + wn * 32;
#pragma unroll
    for (int i = 0; i < 4; ++i) {
#pragma unroll
      for (int j = 0; j < 4; ++j) {
        const int r = bm + wm * 64 + i * 16 + fq * 4 + j;
        if (!accum) {
          float g8[NEXP];
#pragma unroll
          for (int e = 0; e < NEXP; ++e) g8[e] = gate[(size_t)r * NEXP + e];
#pragma unroll
          for (int n = 0; n < 2; ++n) {
            float v = acc[NH][i][n][j];
#pragma unroll
            for (int e = 0; e < NEXP; ++e) v += g8[e] * b2c[NH][n][e];
            Cout[(size_t)r * DDIM + cb0 + n * 16 + fr] = v;
          }
        } else {
#pragma unroll
          for (int n = 0; n < 2; ++n) {
            const size_t idx = (size_t)r * DDIM + cb0 + n * 16 + fr;
            Cout[idx] += acc[NH][i][n][j];
          }
        }
      }
    }
  }
#undef G2_BOFF
#undef G2_SA
#undef G2_SB
#undef G2_RDA_TO
#undef G2_RDB_TO
#undef G2_MMA
#undef G2_ITER
}

extern "C" void kernel_launch(void* const* d_in, const int* in_sizes, int n_in,
                              void* d_out, int out_size, void* d_ws, size_t ws_size,
                              hipStream_t stream) {
  (void)in_sizes; (void)n_in; (void)out_size;
  const float* x  = (const float*)d_in[0];   // [N, D]
  const float* W1 = (const float*)d_in[1];   // [E, D, H]
  const float* b1 = (const float*)d_in[2];   // [E, H]
  const float* W2 = (const float*)d_in[3];   // [E, H, D]
  const float* b2 = (const float*)d_in[4];   // [E, D]
  const float* Wg = (const float*)d_in[5];   // [D, E]
  const float* bg = (const float*)d_in[6];   // [E]
  float* out = (float*)d_out;                // [N, D]

  size_t o_xb   = 0;
  size_t o_w1t  = o_xb  + (size_t)NTOK * DDIM * 2;          // xb   bf16 [N,D]
  size_t o_w2t  = o_w1t + (size_t)NEXP * HDIM * DDIM * 2;   // W1t  bf16 [E*H, D]
  size_t o_gate = o_w2t + (size_t)NEXP * DDIM * HDIM * 2;   // W2t  bf16 [E][D][H]
  size_t o_h    = o_gate + (size_t)NTOK * NEXP * 4;         // gate f32  [N, E]

  int G = 4;                                                 // experts per group
  if (o_h + (size_t)NTOK * G * HDIM * 2 > ws_size) G = 2;
  if (o_h + (size_t)NTOK * G * HDIM * 2 > ws_size) return;

  u16*   xb   = (u16*)((char*)d_ws + o_xb);
  u16*   W1t  = (u16*)((char*)d_ws + o_w1t);
  u16*   W2t  = (u16*)((char*)d_ws + o_w2t);
  float* gate = (float*)((char*)d_ws + o_gate);
  u16*   hbuf = (u16*)((char*)d_ws + o_h);

  k_prep<<<NTOK / 4, 256, 0, stream>>>(x, Wg, bg, xb, gate);
  dim3 g1(DDIM / 64, HDIM / 64, NEXP);
  k_transpose<<<g1, 256, 0, stream>>>(W1, W1t, DDIM, HDIM, (size_t)HDIM * DDIM, DDIM);
  dim3 g2(HDIM / 64, DDIM / 64, NEXP);
  k_transpose<<<g2, 256, 0, stream>>>(W2, W2t, HDIM, DDIM, (size_t)DDIM * HDIM, HDIM);

  const int KW = G * HDIM;                     // 8192 or 4096
  const int ca1 = (G == 4) ? 16 : 8;           // XCD chunk rows for GEMM1
  const int cg1 = (G == 4) ? 4 : 2;            // chunk-grid cols for GEMM1
  for (int g = 0; g < NEXP / G; ++g) {
    // GEMM1: grid 32tm x (KW/256)tn
    k_g1<<<(NTOK / 256) * (KW / 256), 512, 0, stream>>>(
        xb, W1t + (size_t)g * KW * DDIM,
        b1 + (size_t)g * KW, gate, g * G, hbuf, KW, ca1, cg1);
    // GEMM2: grid 256, K = KW
    k_g2<<<256, 512, 0, stream>>>(
        hbuf, W2t + (size_t)g * G * DDIM * HDIM,
        b2, gate, out, g > 0, KW, KW / 64);
  }
}